// Round 1
// baseline (4462.304 us; speedup 1.0000x reference)
//
#include <hip/hip_runtime.h>
#include <math.h>

#define NBANDS 31
#define TCOL 64
#define NROW 24
#define FT 257000   // F*T : stride between channels

__constant__ int d_bs[NBANDS] = {0,1,1,2,2,2,3,3,4,5,6,7,8,10,11,13,16,19,23,27,32,38,45,54,64,76,91,108,128,152,181};
__constant__ int d_be[NBANDS] = {2,3,3,3,4,4,5,6,7,8,9,11,12,14,17,20,24,28,33,39,46,55,65,77,92,109,129,153,182,216,257};

__device__ __forceinline__ void fma8(float& acc, const float* __restrict__ w, const float* __restrict__ x) {
  float4 w0 = *reinterpret_cast<const float4*>(w);
  float4 w1 = *reinterpret_cast<const float4*>(w + 4);
  acc = fmaf(w0.x, x[0], acc); acc = fmaf(w0.y, x[1], acc);
  acc = fmaf(w0.z, x[2], acc); acc = fmaf(w0.w, x[3], acc);
  acc = fmaf(w1.x, x[4], acc); acc = fmaf(w1.y, x[5], acc);
  acc = fmaf(w1.z, x[6], acc); acc = fmaf(w1.w, x[7], acc);
}

// ---- tiny kernel: qp = doa @ dqg_w[k].T + dqg_b[k]; store (1+gamma | beta) ----
__global__ __launch_bounds__(192) void qp_kernel(const float* __restrict__ doa,
                                                 const float* __restrict__ dqg_w,
                                                 const float* __restrict__ dqg_b,
                                                 float* __restrict__ gbuf) {
  const int k = blockIdx.x, b = blockIdx.y;
  const int tid = threadIdx.x;  // 0..191
  __shared__ float sdoa[36];
  if (tid < 36) sdoa[tid] = doa[b * 36 + tid];
  __syncthreads();
  const float* wr = dqg_w + (k * 192 + tid) * 36;
  float acc = dqg_b[k * 192 + tid];
  #pragma unroll
  for (int i = 0; i < 36; ++i) acc = fmaf(wr[i], sdoa[i], acc);
  if (tid < 96) acc += 1.0f;           // store (1+gamma) for first 96
  gbuf[(k * 4 + b) * 192 + tid] = acc;
}

// ---- fused: band enc/LN/FiLM/dec/LN + overlap-add + QKVO attention ----
__global__ __launch_bounds__(256) void fused_kernel(
    const float* __restrict__ mix,  const float* __restrict__ spin,
    const float* __restrict__ enc_w, const float* __restrict__ enc_b, const float* __restrict__ enc_a,
    const float* __restrict__ dec_w, const float* __restrict__ dec_b, const float* __restrict__ dec_a,
    const float* __restrict__ gb,
    const float* __restrict__ qw, const float* __restrict__ qb,
    const float* __restrict__ kw, const float* __restrict__ kb,
    const float* __restrict__ vw, const float* __restrict__ vb,
    const float* __restrict__ ow, const float* __restrict__ ob,
    float* __restrict__ out) {
  const int f  = blockIdx.y;
  const int b  = blockIdx.z;
  const int t0 = blockIdx.x * TCOL;
  const int tid  = threadIdx.x;
  const int lane = tid & 63;
  const int wv   = __builtin_amdgcn_readfirstlane(tid >> 6);  // 0..3, wave-uniform
  const int row0 = wv * NROW;
  const bool tvalid = (t0 + lane) < 1000;
  const int tj = tvalid ? (t0 + lane) : 999;  // clamp; invalid columns discarded at store

  __shared__ float Xt[96 * TCOL];      // tgt, later reused as attended (A)
  __shared__ float G[96 * TCOL];       // merged columns
  __shared__ float red[2][4][TCOL];
  __shared__ float mr[2][TCOL];
  __shared__ float attnb[TCOL];

  // wsum for this bin (uniform; fp64 cos for exactness, negligible cost)
  float wsum = 0.f;
  for (int k = 0; k < NBANDS; ++k) {
    int s = d_bs[k], e = d_be[k];
    if (f >= s && f < e)
      wsum += (float)(0.5 - 0.5 * cos(6.283185307179586 * (double)(f - s) / (double)(e - s)));
  }
  const float winv = 1.0f / fmaxf(wsum, 1e-8f);

  float macc[NROW];
  #pragma unroll
  for (int r = 0; r < NROW; ++r) macc[r] = 0.f;

  // ---------------- band loop ----------------
  for (int k = 0; k < NBANDS; ++k) {
    const int s = d_bs[k], e = d_be[k];
    if (f < s || f >= e) continue;
    const float win = (float)(0.5 - 0.5 * cos(6.283185307179586 * (double)(f - s) / (double)(e - s)));

    // enc: feat rows (row0..row0+23) for column lane
    float acc[NROW];
    #pragma unroll
    for (int r = 0; r < NROW; ++r) acc[r] = enc_b[k * 96 + row0 + r];
    {
      const float* sp = spin + b * 64 * FT + f * 1000 + tj;
      for (int c0 = 0; c0 < 64; c0 += 8) {
        float x[8];
        #pragma unroll
        for (int cc = 0; cc < 8; ++cc) x[cc] = sp[(c0 + cc) * FT];
        #pragma unroll
        for (int r = 0; r < NROW; ++r)
          fma8(acc[r], enc_w + (k * 96 + row0 + r) * 64 + c0, x);
      }
    }
    // chan_ln stats over 96 channels of this column
    float sm = 0.f, sq = 0.f;
    #pragma unroll
    for (int r = 0; r < NROW; ++r) { sm += acc[r]; sq = fmaf(acc[r], acc[r], sq); }
    __syncthreads();
    red[0][wv][lane] = sm; red[1][wv][lane] = sq;
    __syncthreads();
    if (tid < TCOL) {
      float s0 = red[0][0][tid] + red[0][1][tid] + red[0][2][tid] + red[0][3][tid];
      float s1 = red[1][0][tid] + red[1][1][tid] + red[1][2][tid] + red[1][3][tid];
      float m = s0 * (1.f / 96.f);
      float v = s1 * (1.f / 96.f) - m * m;
      mr[0][tid] = m; mr[1][tid] = rsqrtf(v + 1e-5f);
    }
    __syncthreads();
    {
      const float m1 = mr[0][lane], rs1 = mr[1][lane];
      const float ea = enc_a[k];
      const float* gbk = gb + (k * 4 + b) * 192;
      #pragma unroll
      for (int r = 0; r < NROW; ++r) {
        const int o = row0 + r;
        float x = (acc[r] - m1) * rs1;
        x = (x >= 0.f) ? x : ea * x;
        Xt[o * TCOL + lane] = fmaf(gbk[o], x, gbk[96 + o]);
      }
    }
    __syncthreads();

    // dec: 96x96 from Xt
    float dcc[NROW];
    #pragma unroll
    for (int r = 0; r < NROW; ++r) dcc[r] = dec_b[k * 96 + row0 + r];
    for (int c0 = 0; c0 < 96; c0 += 8) {
      float x[8];
      #pragma unroll
      for (int cc = 0; cc < 8; ++cc) x[cc] = Xt[(c0 + cc) * TCOL + lane];
      #pragma unroll
      for (int r = 0; r < NROW; ++r)
        fma8(dcc[r], dec_w + (k * 96 + row0 + r) * 96 + c0, x);
    }
    sm = 0.f; sq = 0.f;
    #pragma unroll
    for (int r = 0; r < NROW; ++r) { sm += dcc[r]; sq = fmaf(dcc[r], dcc[r], sq); }
    red[0][wv][lane] = sm; red[1][wv][lane] = sq;
    __syncthreads();
    if (tid < TCOL) {
      float s0 = red[0][0][tid] + red[0][1][tid] + red[0][2][tid] + red[0][3][tid];
      float s1 = red[1][0][tid] + red[1][1][tid] + red[1][2][tid] + red[1][3][tid];
      float m = s0 * (1.f / 96.f);
      float v = s1 * (1.f / 96.f) - m * m;
      mr[0][tid] = m; mr[1][tid] = rsqrtf(v + 1e-5f);
    }
    __syncthreads();
    {
      const float m2 = mr[0][lane], rs2 = mr[1][lane];
      const float da = dec_a[k];
      #pragma unroll
      for (int r = 0; r < NROW; ++r) {
        float x = (dcc[r] - m2) * rs2;
        x = (x >= 0.f) ? x : da * x;
        macc[r] = fmaf(win, x, macc[r]);
      }
    }
    __syncthreads();
  }

  // merged columns -> LDS
  #pragma unroll
  for (int r = 0; r < NROW; ++r) G[(row0 + r) * TCOL + lane] = macc[r] * winv;
  __syncthreads();

  // ---------------- Q,K + logit ----------------
  float qa[NROW], ka[NROW];
  #pragma unroll
  for (int r = 0; r < NROW; ++r) { qa[r] = qb[row0 + r]; ka[r] = kb[row0 + r]; }
  {
    const float* mp = mix + b * 96 * FT + f * 1000 + tj;
    for (int c0 = 0; c0 < 96; c0 += 8) {
      float x[8], y[8];
      #pragma unroll
      for (int cc = 0; cc < 8; ++cc) {
        x[cc] = mp[(c0 + cc) * FT];
        y[cc] = G[(c0 + cc) * TCOL + lane];
      }
      #pragma unroll
      for (int r = 0; r < NROW; ++r) {
        fma8(qa[r], qw + (row0 + r) * 96 + c0, x);
        fma8(ka[r], kw + (row0 + r) * 96 + c0, y);
      }
    }
  }
  float p = 0.f;
  #pragma unroll
  for (int r = 0; r < NROW; ++r) p = fmaf(qa[r], ka[r], p);
  red[0][wv][lane] = p;
  __syncthreads();
  if (tid < TCOL) {
    float t = red[0][0][tid] + red[0][1][tid] + red[0][2][tid] + red[0][3][tid];
    t *= 0.10206207261596575f;  // 1/sqrt(96)
    attnb[tid] = 1.f / (1.f + expf(-t));
  }
  __syncthreads();

  // ---------------- V, attended ----------------
  float va[NROW];
  #pragma unroll
  for (int r = 0; r < NROW; ++r) va[r] = vb[row0 + r];
  for (int c0 = 0; c0 < 96; c0 += 8) {
    float y[8];
    #pragma unroll
    for (int cc = 0; cc < 8; ++cc) y[cc] = G[(c0 + cc) * TCOL + lane];
    #pragma unroll
    for (int r = 0; r < NROW; ++r)
      fma8(va[r], vw + (row0 + r) * 96 + c0, y);
  }
  {
    const float at = attnb[lane];
    __syncthreads();  // all G reads done before reusing Xt as A is fine (distinct buffers); barrier orders A writes
    #pragma unroll
    for (int r = 0; r < NROW; ++r) Xt[(row0 + r) * TCOL + lane] = va[r] * at;
  }
  __syncthreads();

  // ---------------- O + residual ----------------
  float oa[NROW];
  #pragma unroll
  for (int r = 0; r < NROW; ++r) oa[r] = ob[row0 + r];
  for (int c0 = 0; c0 < 96; c0 += 8) {
    float x[8];
    #pragma unroll
    for (int cc = 0; cc < 8; ++cc) x[cc] = Xt[(c0 + cc) * TCOL + lane];
    #pragma unroll
    for (int r = 0; r < NROW; ++r)
      fma8(oa[r], ow + (row0 + r) * 96 + c0, x);
  }
  if (tvalid) {
    #pragma unroll
    for (int r = 0; r < NROW; ++r) {
      const int o = row0 + r;
      const int gi = (b * 96 + o) * FT + f * 1000 + t0 + lane;
      out[gi] = mix[gi] + oa[r];
    }
  }
}

extern "C" void kernel_launch(void* const* d_in, const int* in_sizes, int n_in,
                              void* d_out, int out_size, void* d_ws, size_t ws_size,
                              hipStream_t stream) {
  (void)in_sizes; (void)n_in; (void)out_size; (void)ws_size;
  const float* mix   = (const float*)d_in[0];
  const float* spin  = (const float*)d_in[1];
  const float* doa   = (const float*)d_in[2];
  const float* enc_w = (const float*)d_in[3];
  const float* enc_b = (const float*)d_in[4];
  const float* enc_a = (const float*)d_in[5];
  const float* dqg_w = (const float*)d_in[6];
  const float* dqg_b = (const float*)d_in[7];
  const float* dec_w = (const float*)d_in[8];
  const float* dec_b = (const float*)d_in[9];
  const float* dec_a = (const float*)d_in[10];
  const float* qw    = (const float*)d_in[11];
  const float* qb    = (const float*)d_in[12];
  const float* kw    = (const float*)d_in[13];
  const float* kb    = (const float*)d_in[14];
  const float* vw    = (const float*)d_in[15];
  const float* vb    = (const float*)d_in[16];
  const float* oww   = (const float*)d_in[17];
  const float* obb   = (const float*)d_in[18];
  float* outp = (float*)d_out;
  float* gbws = (float*)d_ws;   // 31*4*192 floats = 95 KB

  hipLaunchKernelGGL(qp_kernel, dim3(NBANDS, 4), dim3(192), 0, stream,
                     doa, dqg_w, dqg_b, gbws);
  hipLaunchKernelGGL(fused_kernel, dim3(16, 257, 4), dim3(256), 0, stream,
                     mix, spin, enc_w, enc_b, enc_a, dec_w, dec_b, dec_a, gbws,
                     qw, qb, kw, kb, vw, vb, oww, obb, outp);
}

// Round 2
// 1216.037 us; speedup vs baseline: 3.6695x; 3.6695x over previous
//
#include <hip/hip_runtime.h>
#include <math.h>

#define NBANDS 31
#define FT 257000

typedef __attribute__((ext_vector_type(8))) short bh8;
typedef __attribute__((ext_vector_type(4))) float f4;

__constant__ int d_bs[NBANDS] = {0,1,1,2,2,2,3,3,4,5,6,7,8,10,11,13,16,19,23,27,32,38,45,54,64,76,91,108,128,152,181};
__constant__ int d_be[NBANDS] = {2,3,3,3,4,4,5,6,7,8,9,11,12,14,17,20,24,28,33,39,46,55,65,77,92,109,129,153,182,216,257};

__device__ __forceinline__ unsigned short b16u(float v) {
  __bf16 h = (__bf16)v;
  return __builtin_bit_cast(unsigned short, h);
}
__device__ __forceinline__ unsigned pk2(float a, float b) {
  return (unsigned)b16u(a) | ((unsigned)b16u(b) << 16);
}
__device__ __forceinline__ float hann1(int i, int L) {
  return 0.5f - 0.5f * cosf(6.283185307179586f * (float)i / (float)L);
}

// ---- weight f32 -> bf16 prep into workspace ----
__global__ __launch_bounds__(256) void prep_w(
    const float* __restrict__ enc_w, const float* __restrict__ dec_w,
    const float* __restrict__ qw, const float* __restrict__ kw,
    const float* __restrict__ vw, const float* __restrict__ ow,
    unsigned short* __restrict__ w16) {
  const int stride = gridDim.x * blockDim.x;
  for (int i = blockIdx.x * blockDim.x + threadIdx.x; i < 513024; i += stride) {
    float v;
    if (i < 190464) v = enc_w[i];
    else if (i < 476160) v = dec_w[i - 190464];
    else {
      int j = i - 476160;
      int a = j / 9216, o = j - a * 9216;
      v = (a == 0) ? qw[o] : (a == 1) ? kw[o] : (a == 2) ? vw[o] : ow[o];
    }
    w16[i] = b16u(v);
  }
}

// ---- qp = doa @ dqg_w[k].T + dqg_b[k]; store (1+gamma | beta) ----
__global__ __launch_bounds__(192) void qp_kernel(const float* __restrict__ doa,
                                                 const float* __restrict__ dqg_w,
                                                 const float* __restrict__ dqg_b,
                                                 float* __restrict__ gbuf) {
  const int k = blockIdx.x, b = blockIdx.y;
  const int tid = threadIdx.x;
  __shared__ float sdoa[36];
  if (tid < 36) sdoa[tid] = doa[b * 36 + tid];
  __syncthreads();
  const float* wr = dqg_w + (k * 192 + tid) * 36;
  float acc = dqg_b[k * 192 + tid];
  #pragma unroll
  for (int i = 0; i < 36; ++i) acc = fmaf(wr[i], sdoa[i], acc);
  if (tid < 96) acc += 1.0f;
  gbuf[(k * 4 + b) * 192 + tid] = acc;
}

#define LDSWAIT asm volatile("s_waitcnt lgkmcnt(0)" ::: "memory")

// ---- fully fused MFMA kernel: one block = (64 t-cols, f, b) ----
__global__ __launch_bounds__(256) void fused_mfma(
    const float* __restrict__ mix, const float* __restrict__ spin,
    const unsigned short* __restrict__ enc16, const float* __restrict__ enc_b, const float* __restrict__ enc_a,
    const unsigned short* __restrict__ dec16, const float* __restrict__ dec_b, const float* __restrict__ dec_a,
    const float* __restrict__ gb,
    const unsigned short* __restrict__ q16, const float* __restrict__ qb,
    const unsigned short* __restrict__ k16, const float* __restrict__ kb,
    const unsigned short* __restrict__ v16, const float* __restrict__ vb,
    const unsigned short* __restrict__ o16, const float* __restrict__ ob,
    float* __restrict__ out) {
  const int f  = blockIdx.y;
  const int b  = blockIdx.z;
  const int t0 = blockIdx.x << 6;
  const int tid  = threadIdx.x;
  const int lane = tid & 63;
  const int w    = tid >> 6;        // wave 0..3 owns cols [16w,16w+16)
  const int g    = lane >> 4;       // lane group 0..3
  const int n    = lane & 15;
  const int col  = (w << 4) + n;
  const int t    = t0 + col;
  const bool tv  = t < 1000;
  const int tcl  = tv ? t : 999;

  // per-column channel strips, [col][96 chans] bf16 (192B rows)
  __shared__ unsigned short XT[64 * 96];
  __shared__ unsigned short GT[64 * 96];
  unsigned short* xw = XT + col * 96;
  unsigned short* gw = GT + col * 96;

  float wsum = 0.f;
  for (int k = 0; k < NBANDS; ++k) {
    const int s = d_bs[k], e = d_be[k];
    if (f >= s && f < e) wsum += hann1(f - s, e - s);
  }
  const float winv = 1.0f / fmaxf(wsum, 1e-8f);

  f4 macc[6];
  #pragma unroll
  for (int mt = 0; mt < 6; ++mt) macc[mt] = (f4){0.f, 0.f, 0.f, 0.f};

  const float* spL = spin + b * 64 * FT + f * 1000 + tcl;
  const float* mxL = mix  + b * 96 * FT + f * 1000 + tcl;

  // ---------------- band loop ----------------
  for (int k = 0; k < NBANDS; ++k) {
    const int s = d_bs[k], e = d_be[k];
    if (f < s || f >= e) continue;
    const float win = hann1(f - s, e - s);

    // ---- enc: 96x64 ----
    f4 acc[6];
    #pragma unroll
    for (int mt = 0; mt < 6; ++mt) {
      const float4 bb = *reinterpret_cast<const float4*>(enc_b + k * 96 + mt * 16 + g * 4);
      acc[mt] = (f4){bb.x, bb.y, bb.z, bb.w};
    }
    const unsigned short* ew = enc16 + k * (96 * 64);
    #pragma unroll
    for (int kt = 0; kt < 2; ++kt) {
      bh8 bf;
      {
        const float* p = spL + (kt * 32 + g * 8) * FT;
        #pragma unroll
        for (int j = 0; j < 8; ++j) bf[j] = (short)b16u(p[j * FT]);
      }
      #pragma unroll
      for (int mt = 0; mt < 6; ++mt) {
        const bh8 af = *reinterpret_cast<const bh8*>(ew + (mt * 16 + n) * 64 + kt * 32 + g * 8);
        acc[mt] = __builtin_amdgcn_mfma_f32_16x16x32_bf16(af, bf, acc[mt], 0, 0, 0);
      }
    }
    // chan LN (per column, over 96 chans) via shfl reduce
    float sm = 0.f, sq = 0.f;
    #pragma unroll
    for (int mt = 0; mt < 6; ++mt)
      #pragma unroll
      for (int r = 0; r < 4; ++r) { const float v = acc[mt][r]; sm += v; sq = fmaf(v, v, sq); }
    sm += __shfl_xor(sm, 16); sm += __shfl_xor(sm, 32);
    sq += __shfl_xor(sq, 16); sq += __shfl_xor(sq, 32);
    const float mean = sm * (1.f / 96.f);
    const float rs = rsqrtf(sq * (1.f / 96.f) - mean * mean + 1e-5f);
    const float ea = enc_a[k];
    const float* gbk = gb + (k * 4 + b) * 192;
    #pragma unroll
    for (int mt = 0; mt < 6; ++mt) {
      const float4 ga = *reinterpret_cast<const float4*>(gbk + mt * 16 + g * 4);
      const float4 be = *reinterpret_cast<const float4*>(gbk + 96 + mt * 16 + g * 4);
      float x0 = (acc[mt][0] - mean) * rs; x0 = (x0 >= 0.f) ? x0 : ea * x0;
      float x1 = (acc[mt][1] - mean) * rs; x1 = (x1 >= 0.f) ? x1 : ea * x1;
      float x2 = (acc[mt][2] - mean) * rs; x2 = (x2 >= 0.f) ? x2 : ea * x2;
      float x3 = (acc[mt][3] - mean) * rs; x3 = (x3 >= 0.f) ? x3 : ea * x3;
      uint2 u;
      u.x = pk2(fmaf(ga.x, x0, be.x), fmaf(ga.y, x1, be.y));
      u.y = pk2(fmaf(ga.z, x2, be.z), fmaf(ga.w, x3, be.w));
      *reinterpret_cast<uint2*>(xw + mt * 16 + g * 4) = u;
    }
    LDSWAIT;

    // ---- dec: 96x96 from XT ----
    f4 dacc[6];
    #pragma unroll
    for (int mt = 0; mt < 6; ++mt) {
      const float4 bb = *reinterpret_cast<const float4*>(dec_b + k * 96 + mt * 16 + g * 4);
      dacc[mt] = (f4){bb.x, bb.y, bb.z, bb.w};
    }
    const unsigned short* dwp = dec16 + k * (96 * 96);
    #pragma unroll
    for (int kt = 0; kt < 3; ++kt) {
      const bh8 bf = *reinterpret_cast<const bh8*>(xw + kt * 32 + g * 8);
      #pragma unroll
      for (int mt = 0; mt < 6; ++mt) {
        const bh8 af = *reinterpret_cast<const bh8*>(dwp + (mt * 16 + n) * 96 + kt * 32 + g * 8);
        dacc[mt] = __builtin_amdgcn_mfma_f32_16x16x32_bf16(af, bf, dacc[mt], 0, 0, 0);
      }
    }
    float sm2 = 0.f, sq2 = 0.f;
    #pragma unroll
    for (int mt = 0; mt < 6; ++mt)
      #pragma unroll
      for (int r = 0; r < 4; ++r) { const float v = dacc[mt][r]; sm2 += v; sq2 = fmaf(v, v, sq2); }
    sm2 += __shfl_xor(sm2, 16); sm2 += __shfl_xor(sm2, 32);
    sq2 += __shfl_xor(sq2, 16); sq2 += __shfl_xor(sq2, 32);
    const float mean2 = sm2 * (1.f / 96.f);
    const float rs2 = rsqrtf(sq2 * (1.f / 96.f) - mean2 * mean2 + 1e-5f);
    const float da = dec_a[k];
    #pragma unroll
    for (int mt = 0; mt < 6; ++mt)
      #pragma unroll
      for (int r = 0; r < 4; ++r) {
        float x = (dacc[mt][r] - mean2) * rs2;
        x = (x >= 0.f) ? x : da * x;
        macc[mt][r] = fmaf(win, x, macc[mt][r]);
      }
  }

  // ---- merged -> GT (bf16) ----
  #pragma unroll
  for (int mt = 0; mt < 6; ++mt) {
    uint2 u;
    u.x = pk2(macc[mt][0] * winv, macc[mt][1] * winv);
    u.y = pk2(macc[mt][2] * winv, macc[mt][3] * winv);
    *reinterpret_cast<uint2*>(gw + mt * 16 + g * 4) = u;
  }
  LDSWAIT;

  // ---- Q (B from mix, global) ----
  f4 qacc[6];
  #pragma unroll
  for (int mt = 0; mt < 6; ++mt) {
    const float4 bb = *reinterpret_cast<const float4*>(qb + mt * 16 + g * 4);
    qacc[mt] = (f4){bb.x, bb.y, bb.z, bb.w};
  }
  #pragma unroll
  for (int kt = 0; kt < 3; ++kt) {
    bh8 bf;
    {
      const float* p = mxL + (kt * 32 + g * 8) * FT;
      #pragma unroll
      for (int j = 0; j < 8; ++j) bf[j] = (short)b16u(p[j * FT]);
    }
    #pragma unroll
    for (int mt = 0; mt < 6; ++mt) {
      const bh8 af = *reinterpret_cast<const bh8*>(q16 + (mt * 16 + n) * 96 + kt * 32 + g * 8);
      qacc[mt] = __builtin_amdgcn_mfma_f32_16x16x32_bf16(af, bf, qacc[mt], 0, 0, 0);
    }
  }
  // ---- K (B from GT), cache G fragments for V ----
  bh8 gfr[3];
  #pragma unroll
  for (int kt = 0; kt < 3; ++kt) gfr[kt] = *reinterpret_cast<const bh8*>(gw + kt * 32 + g * 8);
  f4 kacc[6];
  #pragma unroll
  for (int mt = 0; mt < 6; ++mt) {
    const float4 bb = *reinterpret_cast<const float4*>(kb + mt * 16 + g * 4);
    kacc[mt] = (f4){bb.x, bb.y, bb.z, bb.w};
  }
  #pragma unroll
  for (int kt = 0; kt < 3; ++kt)
    #pragma unroll
    for (int mt = 0; mt < 6; ++mt) {
      const bh8 af = *reinterpret_cast<const bh8*>(k16 + (mt * 16 + n) * 96 + kt * 32 + g * 8);
      kacc[mt] = __builtin_amdgcn_mfma_f32_16x16x32_bf16(af, gfr[kt], kacc[mt], 0, 0, 0);
    }
  // logit + sigmoid (per column)
  float p = 0.f;
  #pragma unroll
  for (int mt = 0; mt < 6; ++mt)
    #pragma unroll
    for (int r = 0; r < 4; ++r) p = fmaf(qacc[mt][r], kacc[mt][r], p);
  p += __shfl_xor(p, 16); p += __shfl_xor(p, 32);
  const float sig = 1.f / (1.f + __expf(-p * 0.10206207261596575f));

  // ---- V, attended -> XT ----
  f4 vacc[6];
  #pragma unroll
  for (int mt = 0; mt < 6; ++mt) {
    const float4 bb = *reinterpret_cast<const float4*>(vb + mt * 16 + g * 4);
    vacc[mt] = (f4){bb.x, bb.y, bb.z, bb.w};
  }
  #pragma unroll
  for (int kt = 0; kt < 3; ++kt)
    #pragma unroll
    for (int mt = 0; mt < 6; ++mt) {
      const bh8 af = *reinterpret_cast<const bh8*>(v16 + (mt * 16 + n) * 96 + kt * 32 + g * 8);
      vacc[mt] = __builtin_amdgcn_mfma_f32_16x16x32_bf16(af, gfr[kt], vacc[mt], 0, 0, 0);
    }
  #pragma unroll
  for (int mt = 0; mt < 6; ++mt) {
    uint2 u;
    u.x = pk2(vacc[mt][0] * sig, vacc[mt][1] * sig);
    u.y = pk2(vacc[mt][2] * sig, vacc[mt][3] * sig);
    *reinterpret_cast<uint2*>(xw + mt * 16 + g * 4) = u;
  }
  LDSWAIT;

  // ---- O + residual ----
  f4 oacc[6];
  #pragma unroll
  for (int mt = 0; mt < 6; ++mt) {
    const float4 bb = *reinterpret_cast<const float4*>(ob + mt * 16 + g * 4);
    oacc[mt] = (f4){bb.x, bb.y, bb.z, bb.w};
  }
  #pragma unroll
  for (int kt = 0; kt < 3; ++kt) {
    const bh8 bf = *reinterpret_cast<const bh8*>(xw + kt * 32 + g * 8);
    #pragma unroll
    for (int mt = 0; mt < 6; ++mt) {
      const bh8 af = *reinterpret_cast<const bh8*>(o16 + (mt * 16 + n) * 96 + kt * 32 + g * 8);
      oacc[mt] = __builtin_amdgcn_mfma_f32_16x16x32_bf16(af, bf, oacc[mt], 0, 0, 0);
    }
  }
  if (tv) {
    #pragma unroll
    for (int mt = 0; mt < 6; ++mt) {
      const int base = (b * 96 + mt * 16 + g * 4) * FT + f * 1000 + t;
      #pragma unroll
      for (int r = 0; r < 4; ++r) out[base + r * FT] = mix[base + r * FT] + oacc[mt][r];
    }
  }
}

extern "C" void kernel_launch(void* const* d_in, const int* in_sizes, int n_in,
                              void* d_out, int out_size, void* d_ws, size_t ws_size,
                              hipStream_t stream) {
  (void)in_sizes; (void)n_in; (void)out_size; (void)ws_size;
  const float* mix   = (const float*)d_in[0];
  const float* spin  = (const float*)d_in[1];
  const float* doa   = (const float*)d_in[2];
  const float* enc_w = (const float*)d_in[3];
  const float* enc_b = (const float*)d_in[4];
  const float* enc_a = (const float*)d_in[5];
  const float* dqg_w = (const float*)d_in[6];
  const float* dqg_b = (const float*)d_in[7];
  const float* dec_w = (const float*)d_in[8];
  const float* dec_b = (const float*)d_in[9];
  const float* dec_a = (const float*)d_in[10];
  const float* qw    = (const float*)d_in[11];
  const float* qb    = (const float*)d_in[12];
  const float* kw    = (const float*)d_in[13];
  const float* kb    = (const float*)d_in[14];
  const float* vw    = (const float*)d_in[15];
  const float* vb    = (const float*)d_in[16];
  const float* oww   = (const float*)d_in[17];
  const float* obb   = (const float*)d_in[18];
  float* outp = (float*)d_out;

  unsigned short* w16 = (unsigned short*)d_ws;
  unsigned short* enc16 = w16;                 // 31*96*64   = 190464
  unsigned short* dec16 = w16 + 190464;        // 31*96*96   = 285696
  unsigned short* q16   = w16 + 476160;        // 9216 each
  unsigned short* k16   = q16 + 9216;
  unsigned short* v16   = k16 + 9216;
  unsigned short* o16   = v16 + 9216;
  float* gbws = (float*)((char*)d_ws + 1026048);  // 31*4*192 f32

  hipLaunchKernelGGL(prep_w, dim3(512), dim3(256), 0, stream,
                     enc_w, dec_w, qw, kw, vw, oww, w16);
  hipLaunchKernelGGL(qp_kernel, dim3(NBANDS, 4), dim3(192), 0, stream,
                     doa, dqg_w, dqg_b, gbws);
  hipLaunchKernelGGL(fused_mfma, dim3(16, 257, 4), dim3(256), 0, stream,
                     mix, spin, enc16, enc_b, enc_a, dec16, dec_b, dec_a, gbws,
                     q16, qb, k16, kb, v16, vb, o16, obb, outp);
}

// Round 3
// 1045.431 us; speedup vs baseline: 4.2684x; 1.1632x over previous
//
#include <hip/hip_runtime.h>
#include <math.h>

#define NBANDS 31
#define FT 257000

typedef __attribute__((ext_vector_type(8))) short bh8;
typedef __attribute__((ext_vector_type(4))) float f4;

__constant__ int d_bs[NBANDS] = {0,1,1,2,2,2,3,3,4,5,6,7,8,10,11,13,16,19,23,27,32,38,45,54,64,76,91,108,128,152,181};
__constant__ int d_be[NBANDS] = {2,3,3,3,4,4,5,6,7,8,9,11,12,14,17,20,24,28,33,39,46,55,65,77,92,109,129,153,182,216,257};

__device__ __forceinline__ unsigned short b16u(float v) {
  __bf16 h = (__bf16)v;
  return __builtin_bit_cast(unsigned short, h);
}
__device__ __forceinline__ unsigned pk2(float a, float b) {
  return (unsigned)b16u(a) | ((unsigned)b16u(b) << 16);
}
__device__ __forceinline__ float hann1(int i, int L) {
  return 0.5f - 0.5f * cosf(6.283185307179586f * (float)i / (float)L);
}

// ---- weight f32 -> bf16 prep into workspace ----
__global__ __launch_bounds__(256) void prep_w(
    const float* __restrict__ enc_w, const float* __restrict__ dec_w,
    const float* __restrict__ qw, const float* __restrict__ kw,
    const float* __restrict__ vw, const float* __restrict__ ow,
    unsigned short* __restrict__ w16) {
  const int stride = gridDim.x * blockDim.x;
  for (int i = blockIdx.x * blockDim.x + threadIdx.x; i < 513024; i += stride) {
    float v;
    if (i < 190464) v = enc_w[i];
    else if (i < 476160) v = dec_w[i - 190464];
    else {
      int j = i - 476160;
      int a = j / 9216, o = j - a * 9216;
      v = (a == 0) ? qw[o] : (a == 1) ? kw[o] : (a == 2) ? vw[o] : ow[o];
    }
    w16[i] = b16u(v);
  }
}

// ---- qp = doa @ dqg_w[k].T + dqg_b[k]; store (1+gamma | beta) ----
__global__ __launch_bounds__(192) void qp_kernel(const float* __restrict__ doa,
                                                 const float* __restrict__ dqg_w,
                                                 const float* __restrict__ dqg_b,
                                                 float* __restrict__ gbuf) {
  const int k = blockIdx.x, b = blockIdx.y;
  const int tid = threadIdx.x;
  __shared__ float sdoa[36];
  if (tid < 36) sdoa[tid] = doa[b * 36 + tid];
  __syncthreads();
  const float* wr = dqg_w + (k * 192 + tid) * 36;
  float acc = dqg_b[k * 192 + tid];
  #pragma unroll
  for (int i = 0; i < 36; ++i) acc = fmaf(wr[i], sdoa[i], acc);
  if (tid < 96) acc += 1.0f;
  gbuf[(k * 4 + b) * 192 + tid] = acc;
}

#define LDSWAIT asm volatile("s_waitcnt lgkmcnt(0)" ::: "memory")

// ---- fully fused MFMA kernel: one block = (64 t-cols, f, b); waves independent ----
__global__ __launch_bounds__(256, 4) void fused_mfma(
    const float* __restrict__ mix, const float* __restrict__ spin,
    const unsigned short* __restrict__ enc16, const float* __restrict__ enc_b, const float* __restrict__ enc_a,
    const unsigned short* __restrict__ dec16, const float* __restrict__ dec_b, const float* __restrict__ dec_a,
    const float* __restrict__ gb,
    const unsigned short* __restrict__ q16, const float* __restrict__ qb,
    const unsigned short* __restrict__ k16, const float* __restrict__ kb,
    const unsigned short* __restrict__ v16, const float* __restrict__ vb,
    const unsigned short* __restrict__ o16, const float* __restrict__ ob,
    float* __restrict__ out) {
  const int f  = blockIdx.y;
  const int b  = blockIdx.z;
  const int t0 = blockIdx.x << 6;
  const int tid  = threadIdx.x;
  const int lane = tid & 63;
  const int w    = tid >> 6;        // wave 0..3 owns cols [16w,16w+16)
  const int g    = lane >> 4;       // lane group 0..3
  const int n    = lane & 15;
  const int col  = (w << 4) + n;
  const int t    = t0 + col;
  const bool tv  = t < 1000;
  const int tcl  = tv ? t : 999;
  const int sw   = (n & 7) << 3;    // XOR swizzle, short units (bytes 4..6)

  // single wave-private scratch: [col][128 shorts] (256B rows -> swizzle keeps <=2-way)
  __shared__ __align__(16) unsigned short XT[64 * 128];
  unsigned short* xw = XT + col * 128;

  float wsum = 0.f;
  for (int k = 0; k < NBANDS; ++k) {
    const int s = d_bs[k], e = d_be[k];
    if (f >= s && f < e) wsum += hann1(f - s, e - s);
  }
  const float winv = 1.0f / fmaxf(wsum, 1e-8f);

  const float* spL = spin + b * 64 * FT + f * 1000 + tcl;
  const float* mxL = mix  + b * 96 * FT + f * 1000 + tcl;

  // ---- prefetch ALL activation inputs up-front (one latency round) ----
  float spf[16];
  #pragma unroll
  for (int j = 0; j < 8; ++j) spf[j]     = spL[(g * 8 + j) * FT];
  #pragma unroll
  for (int j = 0; j < 8; ++j) spf[8 + j] = spL[(32 + g * 8 + j) * FT];
  float mxf[24];
  #pragma unroll
  for (int kt = 0; kt < 3; ++kt)
    #pragma unroll
    for (int j = 0; j < 8; ++j) mxf[kt * 8 + j] = mxL[(kt * 32 + g * 8 + j) * FT];

  bh8 spb[2], mxb[3];
  #pragma unroll
  for (int kt = 0; kt < 2; ++kt)
    #pragma unroll
    for (int j = 0; j < 8; ++j) spb[kt][j] = (short)b16u(spf[kt * 8 + j]);
  #pragma unroll
  for (int kt = 0; kt < 3; ++kt)
    #pragma unroll
    for (int j = 0; j < 8; ++j) mxb[kt][j] = (short)b16u(mxf[kt * 8 + j]);

  f4 macc[6];
  #pragma unroll
  for (int mt = 0; mt < 6; ++mt) macc[mt] = (f4){0.f, 0.f, 0.f, 0.f};

  // ---------------- band loop (B-fragments already in regs) ----------------
  for (int k = 0; k < NBANDS; ++k) {
    const int s = d_bs[k], e = d_be[k];
    if (f < s || f >= e) continue;
    const float win = hann1(f - s, e - s);

    // ---- enc: 96x64 ----
    f4 acc[6];
    #pragma unroll
    for (int mt = 0; mt < 6; ++mt) {
      const float4 bb = *reinterpret_cast<const float4*>(enc_b + k * 96 + mt * 16 + g * 4);
      acc[mt] = (f4){bb.x, bb.y, bb.z, bb.w};
    }
    const unsigned short* ew = enc16 + k * (96 * 64);
    #pragma unroll
    for (int kt = 0; kt < 2; ++kt)
      #pragma unroll
      for (int mt = 0; mt < 6; ++mt) {
        const bh8 af = *reinterpret_cast<const bh8*>(ew + (mt * 16 + n) * 64 + kt * 32 + g * 8);
        acc[mt] = __builtin_amdgcn_mfma_f32_16x16x32_bf16(af, spb[kt], acc[mt], 0, 0, 0);
      }
    // chan LN via shfl reduce
    float sm = 0.f, sq = 0.f;
    #pragma unroll
    for (int mt = 0; mt < 6; ++mt)
      #pragma unroll
      for (int r = 0; r < 4; ++r) { const float v = acc[mt][r]; sm += v; sq = fmaf(v, v, sq); }
    sm += __shfl_xor(sm, 16); sm += __shfl_xor(sm, 32);
    sq += __shfl_xor(sq, 16); sq += __shfl_xor(sq, 32);
    const float mean = sm * (1.f / 96.f);
    const float rs = rsqrtf(sq * (1.f / 96.f) - mean * mean + 1e-5f);
    const float ea = enc_a[k];
    const float* gbk = gb + (k * 4 + b) * 192;
    #pragma unroll
    for (int mt = 0; mt < 6; ++mt) {
      const float4 ga = *reinterpret_cast<const float4*>(gbk + mt * 16 + g * 4);
      const float4 be = *reinterpret_cast<const float4*>(gbk + 96 + mt * 16 + g * 4);
      float x0 = (acc[mt][0] - mean) * rs; x0 = (x0 >= 0.f) ? x0 : ea * x0;
      float x1 = (acc[mt][1] - mean) * rs; x1 = (x1 >= 0.f) ? x1 : ea * x1;
      float x2 = (acc[mt][2] - mean) * rs; x2 = (x2 >= 0.f) ? x2 : ea * x2;
      float x3 = (acc[mt][3] - mean) * rs; x3 = (x3 >= 0.f) ? x3 : ea * x3;
      uint2 u;
      u.x = pk2(fmaf(ga.x, x0, be.x), fmaf(ga.y, x1, be.y));
      u.y = pk2(fmaf(ga.z, x2, be.z), fmaf(ga.w, x3, be.w));
      *reinterpret_cast<uint2*>(xw + (((mt * 16 + g * 4)) ^ sw)) = u;
    }
    LDSWAIT;

    // ---- dec: 96x96 from XT ----
    f4 dacc[6];
    #pragma unroll
    for (int mt = 0; mt < 6; ++mt) {
      const float4 bb = *reinterpret_cast<const float4*>(dec_b + k * 96 + mt * 16 + g * 4);
      dacc[mt] = (f4){bb.x, bb.y, bb.z, bb.w};
    }
    const unsigned short* dwp = dec16 + k * (96 * 96);
    #pragma unroll
    for (int kt = 0; kt < 3; ++kt) {
      const bh8 bf = *reinterpret_cast<const bh8*>(xw + ((kt * 32 + g * 8) ^ sw));
      #pragma unroll
      for (int mt = 0; mt < 6; ++mt) {
        const bh8 af = *reinterpret_cast<const bh8*>(dwp + (mt * 16 + n) * 96 + kt * 32 + g * 8);
        dacc[mt] = __builtin_amdgcn_mfma_f32_16x16x32_bf16(af, bf, dacc[mt], 0, 0, 0);
      }
    }
    float sm2 = 0.f, sq2 = 0.f;
    #pragma unroll
    for (int mt = 0; mt < 6; ++mt)
      #pragma unroll
      for (int r = 0; r < 4; ++r) { const float v = dacc[mt][r]; sm2 += v; sq2 = fmaf(v, v, sq2); }
    sm2 += __shfl_xor(sm2, 16); sm2 += __shfl_xor(sm2, 32);
    sq2 += __shfl_xor(sq2, 16); sq2 += __shfl_xor(sq2, 32);
    const float mean2 = sm2 * (1.f / 96.f);
    const float rs2 = rsqrtf(sq2 * (1.f / 96.f) - mean2 * mean2 + 1e-5f);
    const float da = dec_a[k];
    #pragma unroll
    for (int mt = 0; mt < 6; ++mt)
      #pragma unroll
      for (int r = 0; r < 4; ++r) {
        float x = (dacc[mt][r] - mean2) * rs2;
        x = (x >= 0.f) ? x : da * x;
        macc[mt][r] = fmaf(win, x, macc[mt][r]);
      }
  }

  // ---- merged -> XT (bf16) ----
  #pragma unroll
  for (int mt = 0; mt < 6; ++mt) {
    uint2 u;
    u.x = pk2(macc[mt][0] * winv, macc[mt][1] * winv);
    u.y = pk2(macc[mt][2] * winv, macc[mt][3] * winv);
    *reinterpret_cast<uint2*>(xw + ((mt * 16 + g * 4) ^ sw)) = u;
  }
  LDSWAIT;
  bh8 gfr[3];
  #pragma unroll
  for (int kt = 0; kt < 3; ++kt) gfr[kt] = *reinterpret_cast<const bh8*>(xw + ((kt * 32 + g * 8) ^ sw));
  LDSWAIT;

  // ---- Q (mix fragments in regs), K (merged fragments) ----
  f4 qacc[6];
  #pragma unroll
  for (int mt = 0; mt < 6; ++mt) {
    const float4 bb = *reinterpret_cast<const float4*>(qb + mt * 16 + g * 4);
    qacc[mt] = (f4){bb.x, bb.y, bb.z, bb.w};
  }
  #pragma unroll
  for (int kt = 0; kt < 3; ++kt)
    #pragma unroll
    for (int mt = 0; mt < 6; ++mt) {
      const bh8 af = *reinterpret_cast<const bh8*>(q16 + (mt * 16 + n) * 96 + kt * 32 + g * 8);
      qacc[mt] = __builtin_amdgcn_mfma_f32_16x16x32_bf16(af, mxb[kt], qacc[mt], 0, 0, 0);
    }
  f4 kacc[6];
  #pragma unroll
  for (int mt = 0; mt < 6; ++mt) {
    const float4 bb = *reinterpret_cast<const float4*>(kb + mt * 16 + g * 4);
    kacc[mt] = (f4){bb.x, bb.y, bb.z, bb.w};
  }
  #pragma unroll
  for (int kt = 0; kt < 3; ++kt)
    #pragma unroll
    for (int mt = 0; mt < 6; ++mt) {
      const bh8 af = *reinterpret_cast<const bh8*>(k16 + (mt * 16 + n) * 96 + kt * 32 + g * 8);
      kacc[mt] = __builtin_amdgcn_mfma_f32_16x16x32_bf16(af, gfr[kt], kacc[mt], 0, 0, 0);
    }
  float p = 0.f;
  #pragma unroll
  for (int mt = 0; mt < 6; ++mt)
    #pragma unroll
    for (int r = 0; r < 4; ++r) p = fmaf(qacc[mt][r], kacc[mt][r], p);
  p += __shfl_xor(p, 16); p += __shfl_xor(p, 32);
  const float sig = 1.f / (1.f + __expf(-p * 0.10206207261596575f));

  // issue residual re-read (L2-hit) early so it hides under V/O MFMA
  float mres[6][4];
  #pragma unroll
  for (int mt = 0; mt < 6; ++mt)
    #pragma unroll
    for (int r = 0; r < 4; ++r) mres[mt][r] = mxL[(mt * 16 + g * 4 + r) * FT];

  // ---- V, attended -> XT ----
  f4 vacc[6];
  #pragma unroll
  for (int mt = 0; mt < 6; ++mt) {
    const float4 bb = *reinterpret_cast<const float4*>(vb + mt * 16 + g * 4);
    vacc[mt] = (f4){bb.x, bb.y, bb.z, bb.w};
  }
  #pragma unroll
  for (int kt = 0; kt < 3; ++kt)
    #pragma unroll
    for (int mt = 0; mt < 6; ++mt) {
      const bh8 af = *reinterpret_cast<const bh8*>(v16 + (mt * 16 + n) * 96 + kt * 32 + g * 8);
      vacc[mt] = __builtin_amdgcn_mfma_f32_16x16x32_bf16(af, gfr[kt], vacc[mt], 0, 0, 0);
    }
  #pragma unroll
  for (int mt = 0; mt < 6; ++mt) {
    uint2 u;
    u.x = pk2(vacc[mt][0] * sig, vacc[mt][1] * sig);
    u.y = pk2(vacc[mt][2] * sig, vacc[mt][3] * sig);
    *reinterpret_cast<uint2*>(xw + ((mt * 16 + g * 4) ^ sw)) = u;
  }
  LDSWAIT;

  // ---- O + residual ----
  f4 oacc[6];
  #pragma unroll
  for (int mt = 0; mt < 6; ++mt) {
    const float4 bb = *reinterpret_cast<const float4*>(ob + mt * 16 + g * 4);
    oacc[mt] = (f4){bb.x, bb.y, bb.z, bb.w};
  }
  #pragma unroll
  for (int kt = 0; kt < 3; ++kt) {
    const bh8 bf = *reinterpret_cast<const bh8*>(xw + ((kt * 32 + g * 8) ^ sw));
    #pragma unroll
    for (int mt = 0; mt < 6; ++mt) {
      const bh8 af = *reinterpret_cast<const bh8*>(o16 + (mt * 16 + n) * 96 + kt * 32 + g * 8);
      oacc[mt] = __builtin_amdgcn_mfma_f32_16x16x32_bf16(af, bf, oacc[mt], 0, 0, 0);
    }
  }
  if (tv) {
    #pragma unroll
    for (int mt = 0; mt < 6; ++mt) {
      const int base = (b * 96 + mt * 16 + g * 4) * FT + f * 1000 + t;
      #pragma unroll
      for (int r = 0; r < 4; ++r) out[base + r * FT] = mres[mt][r] + oacc[mt][r];
    }
  }
}

extern "C" void kernel_launch(void* const* d_in, const int* in_sizes, int n_in,
                              void* d_out, int out_size, void* d_ws, size_t ws_size,
                              hipStream_t stream) {
  (void)in_sizes; (void)n_in; (void)out_size; (void)ws_size;
  const float* mix   = (const float*)d_in[0];
  const float* spin  = (const float*)d_in[1];
  const float* doa   = (const float*)d_in[2];
  const float* enc_w = (const float*)d_in[3];
  const float* enc_b = (const float*)d_in[4];
  const float* enc_a = (const float*)d_in[5];
  const float* dqg_w = (const float*)d_in[6];
  const float* dqg_b = (const float*)d_in[7];
  const float* dec_w = (const float*)d_in[8];
  const float* dec_b = (const float*)d_in[9];
  const float* dec_a = (const float*)d_in[10];
  const float* qw    = (const float*)d_in[11];
  const float* qb    = (const float*)d_in[12];
  const float* kw    = (const float*)d_in[13];
  const float* kb    = (const float*)d_in[14];
  const float* vw    = (const float*)d_in[15];
  const float* vb    = (const float*)d_in[16];
  const float* oww   = (const float*)d_in[17];
  const float* obb   = (const float*)d_in[18];
  float* outp = (float*)d_out;

  unsigned short* w16 = (unsigned short*)d_ws;
  unsigned short* enc16 = w16;                 // 31*96*64   = 190464
  unsigned short* dec16 = w16 + 190464;        // 31*96*96   = 285696
  unsigned short* q16   = w16 + 476160;        // 9216 each
  unsigned short* k16   = q16 + 9216;
  unsigned short* v16   = k16 + 9216;
  unsigned short* o16   = v16 + 9216;
  float* gbws = (float*)((char*)d_ws + 1026048);  // 31*4*192 f32

  hipLaunchKernelGGL(prep_w, dim3(512), dim3(256), 0, stream,
                     enc_w, dec_w, qw, kw, vw, oww, w16);
  hipLaunchKernelGGL(qp_kernel, dim3(NBANDS, 4), dim3(192), 0, stream,
                     doa, dqg_w, dqg_b, gbws);
  hipLaunchKernelGGL(fused_mfma, dim3(16, 257, 4), dim3(256), 0, stream,
                     mix, spin, enc16, enc_b, enc_a, dec16, dec_b, dec_a, gbws,
                     q16, qb, k16, kb, v16, vb, o16, obb, outp);
}